// Round 4
// baseline (3201.340 us; speedup 1.0000x reference)
//
#include <hip/hip_runtime.h>
#include <hip/hip_fp16.h>

#define EDIM 256
#define HDIM 512
#define CDIM 50257

using half2_t = __attribute__((ext_vector_type(2))) _Float16;
using half8_t = __attribute__((ext_vector_type(8))) _Float16;
using float4_t = __attribute__((ext_vector_type(4))) float;
typedef half8_t f16x8;

#define MFMA16(a, b, c) __builtin_amdgcn_mfma_f32_16x16x32_f16(a, b, c, 0, 0, 0)

// tanh(x) = 1 - 2/(exp2(2x*log2e)+1): 5 VALU instrs vs ~30 for tanhf libcall
__device__ __forceinline__ float fast_tanh(float x) {
    float e = __builtin_amdgcn_exp2f(x * 2.8853900817779268f);
    return 1.f - 2.f * __builtin_amdgcn_rcpf(e + 1.f);
}

// ---------------------------------------------------------------------------
// Pack whh (f32 [512][512]) into MFMA A-fragments (f16):
// tile T = (w*4 + rt)*16 + kt  (wave w 0..7, r-tile rt 0..3, k-tile kt 0..15)
// lane l elem e: W[w*64 + rt*16 + (l&15)][kt*32 + (l>>4)*8 + e]
// flat: wpack_u4[T*64 + l] = 8 packed halves.
// ---------------------------------------------------------------------------
__global__ void __launch_bounds__(256) pack_whh(const float* __restrict__ whh,
                                                _Float16* __restrict__ wpack) {
    int idx = blockIdx.x * blockDim.x + threadIdx.x;   // 0..32767
    int T = idx >> 6, l = idx & 63;
    int w = T >> 6, rt = (T >> 4) & 3, kt = T & 15;
    int row = w * 64 + rt * 16 + (l & 15);
    int k0 = kt * 32 + ((l >> 4) << 3);
    const float* src = whh + row * HDIM + k0;
    uint32_t d[4];
#pragma unroll
    for (int q = 0; q < 4; ++q) {
        half2_t p;
        p[0] = (_Float16)src[2 * q];
        p[1] = (_Float16)src[2 * q + 1];
        d[q] = __builtin_bit_cast(uint32_t, p);
    }
    ((uint4*)wpack)[T * 64 + l] = make_uint4(d[0], d[1], d[2], d[3]);
}

// ---------------------------------------------------------------------------
// z[t][r] = dot(wih[r,:], emb[id_t]) + bih[r] + bhh[r]   (fp32, parallel)
// ---------------------------------------------------------------------------
__global__ void __launch_bounds__(256) zker(const int* __restrict__ in_ids,
                                            const int* __restrict__ out_ids,
                                            const float* __restrict__ emb,
                                            const float* __restrict__ enc_wih,
                                            const float* __restrict__ enc_bih,
                                            const float* __restrict__ enc_bhh,
                                            const float* __restrict__ dec_wih,
                                            const float* __restrict__ dec_bih,
                                            const float* __restrict__ dec_bhh,
                                            float* __restrict__ z) {
    int t = blockIdx.x;
    const float *wih, *bih, *bhh;
    int id;
    if (t < 512) {
        wih = enc_wih; bih = enc_bih; bhh = enc_bhh; id = in_ids[t];
    } else {
        wih = dec_wih; bih = dec_bih; bhh = dec_bhh;
        id = (t == 512) ? 1 : out_ids[t - 513];
    }
    __shared__ float x[EDIM];
    x[threadIdx.x] = emb[(long)id * EDIM + threadIdx.x];
    __syncthreads();
#pragma unroll
    for (int rr = 0; rr < 2; ++rr) {
        int r = threadIdx.x + rr * 256;
        const float4* w4 = (const float4*)(wih + r * EDIM);
        float acc = 0.f;
#pragma unroll 8
        for (int k4 = 0; k4 < 64; ++k4) {
            float4 wv = w4[k4];
            acc += wv.x * x[k4 * 4 + 0] + wv.y * x[k4 * 4 + 1] +
                   wv.z * x[k4 * 4 + 2] + wv.w * x[k4 * 4 + 3];
        }
        z[t * HDIM + r] = acc + bih[r] + bhh[r];
    }
}

// ---------------------------------------------------------------------------
// MFMA RNN scan: 1 workgroup, 512 threads (8 waves, 2/SIMD, 256-reg budget).
// Wave w owns rows [w*64, w*64+64): 4 r-tiles x 16 k-tiles of 16x16x32 MFMA.
// A = W tile (AGPR/VGPR resident: kt 0..11; kt 12..15 restreamed from L2 each
// step via 2 rotating 4-tile buffers issued 3-6 k-blocks ahead). B = h
// broadcast from LDS (16-lane-broadcast ds_read_b128, conflict-free). D rows
// are col-replicated -> epilogue: 1 row/lane via 6-cndmask select, fast tanh,
// single b16 LDS write. One barrier per step.
// ---------------------------------------------------------------------------
__global__ void __launch_bounds__(512, 2) scan_ker(
    const _Float16* __restrict__ wpack,   // packed tiles, see pack_whh
    const float* __restrict__ z,          // [nsteps][512] f32
    const _Float16* __restrict__ h_init,  // null => zeros; else [512]
    _Float16* __restrict__ hs_out,        // null or [nsteps][512]
    _Float16* __restrict__ hfin_out,      // null or [512]
    int nsteps) {
    __shared__ _Float16 hbuf[2][512];     // 2 KB

    const int tid = threadIdx.x;
    const int w = tid >> 6, l = tid & 63;
    const int lg8 = ((l >> 4) << 3);      // lane-group * 8 (B-frag elem base)
    // epilogue row owned by this lane (bijective over l within the wave band)
    const int rowl = (((l & 15) >> 2) << 4) + ((l >> 4) << 2) + (l & 3);
    const int grow = w * 64 + rowl;       // global h row

    const f16x8* wp8 = (const f16x8*)wpack;
    // resident A-fragments: kt 0..11
    f16x8 wa0[12], wa1[12], wa2[12], wa3[12];
#pragma unroll
    for (int kt = 0; kt < 12; ++kt) {
        wa0[kt] = wp8[((w * 4 + 0) * 16 + kt) * 64 + l];
        wa1[kt] = wp8[((w * 4 + 1) * 16 + kt) * 64 + l];
        wa2[kt] = wp8[((w * 4 + 2) * 16 + kt) * 64 + l];
        wa3[kt] = wp8[((w * 4 + 3) * 16 + kt) * 64 + l];
    }
    // stream bases at kt=12 (imm offsets 0,1024,2048,3072 B for kt 12..15)
    const f16x8* p0 = wp8 + ((w * 4 + 0) * 16 + 12) * 64 + l;
    const f16x8* p1 = wp8 + ((w * 4 + 1) * 16 + 12) * 64 + l;
    const f16x8* p2 = wp8 + ((w * 4 + 2) * 16 + 12) * 64 + l;
    const f16x8* p3 = wp8 + ((w * 4 + 3) * 16 + 12) * 64 + l;

    hbuf[0][tid] = h_init ? h_init[tid] : (_Float16)0.f;
    __syncthreads();

    int cur = 0;
    for (int t = 0; t < nsteps; ++t) {
        float zv = z[t * HDIM + grow];                 // early VMEM issue
        const _Float16* hb = hbuf[0] + cur * 512;
        // issue stream batch A (kt=12) and B (kt=13) at step top
        f16x8 sA0 = p0[0],      sA1 = p1[0],      sA2 = p2[0],      sA3 = p3[0];
        f16x8 sB0 = p0[1 * 64], sB1 = p1[1 * 64], sB2 = p2[1 * 64], sB3 = p3[1 * 64];

        float4_t acc0 = {0.f, 0.f, 0.f, 0.f}, acc1 = {0.f, 0.f, 0.f, 0.f};
        float4_t acc2 = {0.f, 0.f, 0.f, 0.f}, acc3 = {0.f, 0.f, 0.f, 0.f};

#define RES_KT(kt) do {                                                        \
        f16x8 bf = *(const f16x8*)(hb + (kt) * 32 + lg8);                      \
        acc0 = MFMA16(wa0[kt], bf, acc0);                                      \
        acc1 = MFMA16(wa1[kt], bf, acc1);                                      \
        acc2 = MFMA16(wa2[kt], bf, acc2);                                      \
        acc3 = MFMA16(wa3[kt], bf, acc3); } while (0)
#define STR_KT(kt, s0, s1, s2, s3) do {                                        \
        f16x8 bf = *(const f16x8*)(hb + (kt) * 32 + lg8);                      \
        acc0 = MFMA16(s0, bf, acc0);                                           \
        acc1 = MFMA16(s1, bf, acc1);                                           \
        acc2 = MFMA16(s2, bf, acc2);                                           \
        acc3 = MFMA16(s3, bf, acc3); } while (0)

        RES_KT(0); RES_KT(1); RES_KT(2); RES_KT(3); RES_KT(4); RES_KT(5);
        STR_KT(12, sA0, sA1, sA2, sA3);                 // consume batch A
        sA0 = p0[2 * 64]; sA1 = p1[2 * 64];             // reissue A <- kt14
        sA2 = p2[2 * 64]; sA3 = p3[2 * 64];
        RES_KT(6); RES_KT(7); RES_KT(8);
        STR_KT(13, sB0, sB1, sB2, sB3);                 // consume batch B
        sB0 = p0[3 * 64]; sB1 = p1[3 * 64];             // reissue B <- kt15
        sB2 = p2[3 * 64]; sB3 = p3[3 * 64];
        RES_KT(9); RES_KT(10); RES_KT(11);
        STR_KT(14, sA0, sA1, sA2, sA3);
        STR_KT(15, sB0, sB1, sB2, sB3);
#undef RES_KT
#undef STR_KT
        // epilogue: lane l owns row rowl = 16*rt' + 4*(l>>4) + q'
        float4_t arl = (l & 4) ? acc1 : acc0;
        float4_t arh = (l & 4) ? acc3 : acc2;
        float4_t ar  = (l & 8) ? arh : arl;
        float v01 = (l & 1) ? ar[1] : ar[0];
        float v23 = (l & 1) ? ar[3] : ar[2];
        float v   = (l & 2) ? v23 : v01;

        float hnew = fast_tanh(v + zv);
        _Float16 h16v = (_Float16)hnew;
        hbuf[cur ^ 1][grow] = h16v;
        if (hs_out) hs_out[t * HDIM + grow] = h16v;
        if (hfin_out && t == nsteps - 1) hfin_out[grow] = h16v;
        __syncthreads();
        cur ^= 1;
    }
}

// ---------------------------------------------------------------------------
// Convert fc_w f32 -> f16 once
// ---------------------------------------------------------------------------
__global__ void __launch_bounds__(256) cvt_w16(const float* __restrict__ src,
                                               _Float16* __restrict__ dst, long n) {
    long i = ((long)blockIdx.x * 256 + threadIdx.x) * 8;
    if (i + 8 <= n) {
        const float4* s4 = (const float4*)(src + i);
        float4 a = s4[0], b = s4[1];
        half8_t o;
        o[0] = (_Float16)a.x; o[1] = (_Float16)a.y;
        o[2] = (_Float16)a.z; o[3] = (_Float16)a.w;
        o[4] = (_Float16)b.x; o[5] = (_Float16)b.y;
        o[6] = (_Float16)b.z; o[7] = (_Float16)b.w;
        *(half8_t*)(dst + i) = o;
    }
}

// ---------------------------------------------------------------------------
// FC: out[m][n] = sum_k A16[m][k] * B16[n][k] + fc_b[n]
// M=512, N=50257, K=512. f16 MFMA 16x16x32, direct global frags (B is f16).
// ---------------------------------------------------------------------------
__global__ void __launch_bounds__(256) fc_ker16(const _Float16* __restrict__ A,
                                                const _Float16* __restrict__ Bw,
                                                const float* __restrict__ bias,
                                                float* __restrict__ out) {
    int n0 = blockIdx.x * 128, m0 = blockIdx.y * 128;
    int w = threadIdx.x >> 6, l = threadIdx.x & 63;
    int wm = (w >> 1) * 64, wn = (w & 1) * 64;
    int lr = l & 15, lk = (l >> 4) * 8;

    float4_t acc[4][4];
#pragma unroll
    for (int fm = 0; fm < 4; ++fm)
#pragma unroll
        for (int fn = 0; fn < 4; ++fn) acc[fm][fn] = (float4_t){0.f, 0.f, 0.f, 0.f};

    for (int ks = 0; ks < 512; ks += 32) {
        half8_t a[4], b[4];
#pragma unroll
        for (int f = 0; f < 4; ++f) {
            int m = m0 + wm + f * 16 + lr;
            a[f] = *(const half8_t*)(A + (long)m * 512 + ks + lk);
            int n = n0 + wn + f * 16 + lr;
            if (n < CDIM) {
                b[f] = *(const half8_t*)(Bw + (long)n * 512 + ks + lk);
            } else {
#pragma unroll
                for (int e = 0; e < 8; ++e) b[f][e] = (_Float16)0.f;
            }
        }
#pragma unroll
        for (int fm = 0; fm < 4; ++fm)
#pragma unroll
            for (int fn = 0; fn < 4; ++fn)
                acc[fm][fn] = __builtin_amdgcn_mfma_f32_16x16x32_f16(
                    a[fm], b[fn], acc[fm][fn], 0, 0, 0);
    }
#pragma unroll
    for (int fn = 0; fn < 4; ++fn) {
        int n = n0 + wn + fn * 16 + lr;
        if (n >= CDIM) continue;
        float bv = bias[n];
#pragma unroll
        for (int fm = 0; fm < 4; ++fm) {
#pragma unroll
            for (int q = 0; q < 4; ++q) {
                int m = m0 + wm + fm * 16 + (l >> 4) * 4 + q;
                out[(long)m * CDIM + n] = acc[fm][fn][q] + bv;
            }
        }
    }
}

// Fallback FC reading f32 B with inline conversion (if ws too small for f16 B)
__global__ void __launch_bounds__(256) fc_ker(const _Float16* __restrict__ A,
                                              const float* __restrict__ Bw,
                                              const float* __restrict__ bias,
                                              float* __restrict__ out) {
    int n0 = blockIdx.x * 128, m0 = blockIdx.y * 128;
    int w = threadIdx.x >> 6, l = threadIdx.x & 63;
    int wm = (w >> 1) * 64, wn = (w & 1) * 64;
    int lr = l & 15, lk = (l >> 4) * 8;

    float4_t acc[4][4];
#pragma unroll
    for (int fm = 0; fm < 4; ++fm)
#pragma unroll
        for (int fn = 0; fn < 4; ++fn) acc[fm][fn] = (float4_t){0.f, 0.f, 0.f, 0.f};

    for (int ks = 0; ks < 512; ks += 32) {
        half8_t a[4], b[4];
#pragma unroll
        for (int f = 0; f < 4; ++f) {
            int m = m0 + wm + f * 16 + lr;
            a[f] = *(const half8_t*)(A + (long)m * 512 + ks + lk);
            int n = n0 + wn + f * 16 + lr;
            half8_t bb;
            if (n < CDIM) {
                const float4* bp4 = (const float4*)(Bw + (long)n * 512 + ks + lk);
                float4 x0 = bp4[0], x1 = bp4[1];
                bb[0] = (_Float16)x0.x; bb[1] = (_Float16)x0.y;
                bb[2] = (_Float16)x0.z; bb[3] = (_Float16)x0.w;
                bb[4] = (_Float16)x1.x; bb[5] = (_Float16)x1.y;
                bb[6] = (_Float16)x1.z; bb[7] = (_Float16)x1.w;
            } else {
#pragma unroll
                for (int e = 0; e < 8; ++e) bb[e] = (_Float16)0.f;
            }
            b[f] = bb;
        }
#pragma unroll
        for (int fm = 0; fm < 4; ++fm)
#pragma unroll
            for (int fn = 0; fn < 4; ++fn)
                acc[fm][fn] = __builtin_amdgcn_mfma_f32_16x16x32_f16(
                    a[fm], b[fn], acc[fm][fn], 0, 0, 0);
    }
#pragma unroll
    for (int fn = 0; fn < 4; ++fn) {
        int n = n0 + wn + fn * 16 + lr;
        if (n >= CDIM) continue;
        float bv = bias[n];
#pragma unroll
        for (int fm = 0; fm < 4; ++fm) {
#pragma unroll
            for (int q = 0; q < 4; ++q) {
                int m = m0 + wm + fm * 16 + (l >> 4) * 4 + q;
                out[(long)m * CDIM + n] = acc[fm][fn][q] + bv;
            }
        }
    }
}

// ---------------------------------------------------------------------------
// Workspace layout:
//   [0, 2MB)          z  f32 [1024][512]
//   [2MB, 2.5MB)      wpack_enc f16 (512 tiles x 64 lanes x 16B)
//   [2.5MB, 3MB)      wpack_dec f16
//   [3MB, 3.5MB)      h16 f16 [512][512]  (decoder hidden states = FC A matrix)
//   [3.5MB, +1KB)     hn16 f16 [512]      (encoder final hidden)
//   [4MB, 4MB+51.5MB) fc_w16 (only if ws_size permits)
// ---------------------------------------------------------------------------
extern "C" void kernel_launch(void* const* d_in, const int* in_sizes, int n_in,
                              void* d_out, int out_size, void* d_ws, size_t ws_size,
                              hipStream_t stream) {
    const int* input_ids  = (const int*)d_in[1];
    const int* output_ids = (const int*)d_in[2];
    const float* emb      = (const float*)d_in[3];
    const float* enc_wih  = (const float*)d_in[4];
    const float* enc_whh  = (const float*)d_in[5];
    const float* enc_bih  = (const float*)d_in[6];
    const float* enc_bhh  = (const float*)d_in[7];
    const float* dec_wih  = (const float*)d_in[8];
    const float* dec_whh  = (const float*)d_in[9];
    const float* dec_bih  = (const float*)d_in[10];
    const float* dec_bhh  = (const float*)d_in[11];
    const float* fc_w     = (const float*)d_in[12];
    const float* fc_b     = (const float*)d_in[13];
    float* out = (float*)d_out;

    char* ws = (char*)d_ws;
    float* z        = (float*)ws;                                  // 2 MB
    _Float16* wpe   = (_Float16*)(ws + (2u << 20));                // 512 KB
    _Float16* wpd   = (_Float16*)(ws + (2u << 20) + (512u << 10)); // 512 KB
    _Float16* h16   = (_Float16*)(ws + (3u << 20));                // 512 KB
    _Float16* hn16  = (_Float16*)(ws + (3u << 20) + (512u << 10)); // 1 KB
    _Float16* fcw16 = (_Float16*)(ws + (4u << 20));                // 51.5 MB

    const long fcw_n = (long)CDIM * HDIM;
    bool use_f16_fc = ws_size >= (size_t)(4u << 20) + (size_t)fcw_n * 2;

    pack_whh<<<128, 256, 0, stream>>>(enc_whh, wpe);
    pack_whh<<<128, 256, 0, stream>>>(dec_whh, wpd);
    if (use_f16_fc) {
        int nb = (int)((fcw_n / 8 + 255) / 256);
        cvt_w16<<<nb, 256, 0, stream>>>(fc_w, fcw16, fcw_n);
    }
    zker<<<1024, 256, 0, stream>>>(input_ids, output_ids, emb,
                                   enc_wih, enc_bih, enc_bhh,
                                   dec_wih, dec_bih, dec_bhh, z);
    // encoder: h starts at 0, produce hn16
    scan_ker<<<1, 512, 0, stream>>>(wpe, z, nullptr, nullptr, hn16, 512);
    // decoder: h starts at hn16, produce all 512 hidden states
    scan_ker<<<1, 512, 0, stream>>>(wpd, z + 512 * HDIM, hn16, h16, nullptr, 512);
    if (use_f16_fc)
        fc_ker16<<<dim3((CDIM + 127) / 128, 4), 256, 0, stream>>>(h16, fcw16, fc_b, out);
    else
        fc_ker<<<dim3((CDIM + 127) / 128, 4), 256, 0, stream>>>(h16, fc_w, fc_b, out);
}

// Round 5
// 1800.068 us; speedup vs baseline: 1.7785x; 1.7785x over previous
//
#include <hip/hip_runtime.h>
#include <hip/hip_fp16.h>

#define EDIM 256
#define HDIM 512
#define CDIM 50257

using half2_t = __attribute__((ext_vector_type(2))) _Float16;
using half8_t = __attribute__((ext_vector_type(8))) _Float16;
using float4_t = __attribute__((ext_vector_type(4))) float;

__device__ __forceinline__ float dot2(uint32_t w, uint32_t h, float acc) {
    return __builtin_amdgcn_fdot2(__builtin_bit_cast(half2_t, w),
                                  __builtin_bit_cast(half2_t, h), acc, false);
}

// tanh(x) = 1 - 2/(exp2(2x*log2e)+1): ~5 VALU instrs vs ~30 for tanhf libcall
__device__ __forceinline__ float fast_tanh(float x) {
    float e = __builtin_amdgcn_exp2f(x * 2.8853900817779268f);
    return 1.f - 2.f * __builtin_amdgcn_rcpf(e + 1.f);
}

// ---------------------------------------------------------------------------
// Pack whh (f32 [512][512]) into f16 granules [g=0..63][tid=0..511][8 halves]
// scan thread `tid` (rg = tid>>3, c = tid&7) owns rows rg*8+jr, k in [c*64, c*64+64)
// granule g = jr*8 + i  holds  whh[rg*8 + (g>>3)][c*64 + (g&7)*8 + e]
// ---------------------------------------------------------------------------
__global__ void __launch_bounds__(256) pack_whh(const float* __restrict__ whh,
                                                _Float16* __restrict__ wpack) {
    int idx = blockIdx.x * blockDim.x + threadIdx.x;   // 0..32767
    int g = idx >> 9, t = idx & 511;
    int row = ((t >> 3) << 3) + (g >> 3);
    int k0 = ((t & 7) << 6) + ((g & 7) << 3);
    const float* src = whh + row * HDIM + k0;
    uint32_t d[4];
#pragma unroll
    for (int q = 0; q < 4; ++q) {
        half2_t p;
        p[0] = (_Float16)src[2 * q];
        p[1] = (_Float16)src[2 * q + 1];
        d[q] = __builtin_bit_cast(uint32_t, p);
    }
    uint4 v = make_uint4(d[0], d[1], d[2], d[3]);
    ((uint4*)wpack)[g * 512 + t] = v;
}

// ---------------------------------------------------------------------------
// z[t][r] = dot(wih[r,:], emb[id_t]) + bih[r] + bhh[r]   (fp32, parallel)
// ---------------------------------------------------------------------------
__global__ void __launch_bounds__(256) zker(const int* __restrict__ in_ids,
                                            const int* __restrict__ out_ids,
                                            const float* __restrict__ emb,
                                            const float* __restrict__ enc_wih,
                                            const float* __restrict__ enc_bih,
                                            const float* __restrict__ enc_bhh,
                                            const float* __restrict__ dec_wih,
                                            const float* __restrict__ dec_bih,
                                            const float* __restrict__ dec_bhh,
                                            float* __restrict__ z) {
    int t = blockIdx.x;
    const float *wih, *bih, *bhh;
    int id;
    if (t < 512) {
        wih = enc_wih; bih = enc_bih; bhh = enc_bhh; id = in_ids[t];
    } else {
        wih = dec_wih; bih = dec_bih; bhh = dec_bhh;
        id = (t == 512) ? 1 : out_ids[t - 513];
    }
    __shared__ float x[EDIM];
    x[threadIdx.x] = emb[(long)id * EDIM + threadIdx.x];
    __syncthreads();
#pragma unroll
    for (int rr = 0; rr < 2; ++rr) {
        int r = threadIdx.x + rr * 256;
        const float4* w4 = (const float4*)(wih + r * EDIM);
        float acc = 0.f;
#pragma unroll 8
        for (int k4 = 0; k4 < 64; ++k4) {
            float4 wv = w4[k4];
            acc += wv.x * x[k4 * 4 + 0] + wv.y * x[k4 * 4 + 1] +
                   wv.z * x[k4 * 4 + 2] + wv.w * x[k4 * 4 + 3];
        }
        z[t * HDIM + r] = acc + bih[r] + bhh[r];
    }
}

// ---------------------------------------------------------------------------
// Sequential RNN scan: single workgroup, 512 threads (8 waves, 2/SIMD).
// thread tid: rg = tid>>3 (row group), c = tid&7 (k chunk of 64).
// Rows jr=0..5 in wreg (192 words, arch+AGPR); jr=6 streamed from LDS (64 KB);
// jr=7 streamed from L2 with ALL 8 loads hoisted to step top + sched_barrier
// pin, so L2 latency pipelines under the dot2 work (R2 exposed it per-use).
// h f16 in LDS, double-buffered, granule-XOR-swizzled (conflict-free
// broadcast). Folds: xor1/xor2 on VALU via DPP quad_perm; xor4 via
// ds_swizzle. Fast inline tanh. One barrier per step.
// ---------------------------------------------------------------------------
__global__ void __launch_bounds__(512, 2) scan_ker(
    const _Float16* __restrict__ wpack,   // [64][512][8] f16
    const float* __restrict__ z,          // [nsteps][512] f32
    const _Float16* __restrict__ h_init,  // null => zeros; else [512] plain
    _Float16* __restrict__ hs_out,        // null or [nsteps][512] plain
    _Float16* __restrict__ hfin_out,      // null or [512] plain
    int nsteps) {
    __shared__ uint4 wlds[8 * 512];    // 64 KB: row jr=6: [i][tid]
    __shared__ uint4 hbuf[2][64];      // 2 KB: h as f16, swizzled granules

    const int tid = threadIdx.x;
    const int c = tid & 7;
    const int c_of = tid >> 6;
    const int i_of = (tid >> 3) & 7;
    const int hphys = (c_of << 3) | (i_of ^ c_of);

    const uint4* wp4 = (const uint4*)wpack;
    uint32_t wreg[192];                // rows jr=0..5
#pragma unroll
    for (int g = 0; g < 48; ++g) {
        uint4 v = wp4[g * 512 + tid];
        wreg[g * 4 + 0] = v.x; wreg[g * 4 + 1] = v.y;
        wreg[g * 4 + 2] = v.z; wreg[g * 4 + 3] = v.w;
    }
#pragma unroll
    for (int g = 48; g < 56; ++g) wlds[(g - 48) * 512 + tid] = wp4[g * 512 + tid];
    const uint4* w7p = wp4 + 56 * 512 + tid;   // row jr=7 granules: w7p[i*512]

    {
        _Float16 hv = (_Float16)0.f;
        if (h_init) hv = h_init[tid];
        ((_Float16*)hbuf[0])[hphys * 8 + (tid & 7)] = hv;
    }
    __syncthreads();

    int cur = 0;
    for (int t = 0; t < nsteps; ++t) {
        float zv = z[t * HDIM + tid];          // independent: scheduled early
        // hoist ALL row-7 L2 loads to step top; pin them here so the
        // scheduler cannot sink them next to their uses (R2's mistake).
        uint4 w7b[8];
#pragma unroll
        for (int i = 0; i < 8; ++i) w7b[i] = w7p[i * 512];
        __builtin_amdgcn_sched_barrier(0);

        const uint4* hb = hbuf[cur];
        float acc[8] = {0.f, 0.f, 0.f, 0.f, 0.f, 0.f, 0.f, 0.f};
#pragma unroll
        for (int i = 0; i < 8; ++i) {
            uint4 hg = hb[(c << 3) | (i ^ c)];
            uint4 w6 = wlds[i * 512 + tid];
#pragma unroll
            for (int jr = 0; jr < 6; ++jr) {
                acc[jr] = dot2(wreg[(jr * 8 + i) * 4 + 0], hg.x, acc[jr]);
                acc[jr] = dot2(wreg[(jr * 8 + i) * 4 + 1], hg.y, acc[jr]);
                acc[jr] = dot2(wreg[(jr * 8 + i) * 4 + 2], hg.z, acc[jr]);
                acc[jr] = dot2(wreg[(jr * 8 + i) * 4 + 3], hg.w, acc[jr]);
            }
            acc[6] = dot2(w6.x, hg.x, acc[6]);
            acc[6] = dot2(w6.y, hg.y, acc[6]);
            acc[6] = dot2(w6.z, hg.z, acc[6]);
            acc[6] = dot2(w6.w, hg.w, acc[6]);
            acc[7] = dot2(w7b[i].x, hg.x, acc[7]);
            acc[7] = dot2(w7b[i].y, hg.y, acc[7]);
            acc[7] = dot2(w7b[i].z, hg.z, acc[7]);
            acc[7] = dot2(w7b[i].w, hg.w, acc[7]);
        }
        // fold-reduce over lane bits 0..2: lane c ends with row rg*8+c (== tid)
        // xor1/xor2 on the VALU pipe via DPP quad_perm; xor4 via ds_swizzle.
        float s, keep, b0, b1, b2, b3, d0, d1, v;
#define FOLD_DPP(aL, aH, bit, ctrl, dst)                                      \
        s = (c & bit) ? (aL) : (aH);                                          \
        s = __builtin_bit_cast(float, __builtin_amdgcn_mov_dpp(               \
                __builtin_bit_cast(int, s), ctrl, 0xF, 0xF, true));           \
        keep = (c & bit) ? (aH) : (aL);                                       \
        dst = keep + s;
#define FOLD_SWZ(aL, aH, bit, pat, dst)                                       \
        s = (c & bit) ? (aL) : (aH);                                          \
        s = __builtin_bit_cast(float, __builtin_amdgcn_ds_swizzle(            \
                __builtin_bit_cast(int, s), pat));                            \
        keep = (c & bit) ? (aH) : (aL);                                       \
        dst = keep + s;
        FOLD_DPP(acc[0], acc[1], 1, 0xB1, b0)   // quad_perm(1,0,3,2) = xor1
        FOLD_DPP(acc[2], acc[3], 1, 0xB1, b1)
        FOLD_DPP(acc[4], acc[5], 1, 0xB1, b2)
        FOLD_DPP(acc[6], acc[7], 1, 0xB1, b3)
        FOLD_DPP(b0, b1, 2, 0x4E, d0)           // quad_perm(2,3,0,1) = xor2
        FOLD_DPP(b2, b3, 2, 0x4E, d1)
        FOLD_SWZ(d0, d1, 4, 0x101F, v)          // ds_swizzle xor4
#undef FOLD_DPP
#undef FOLD_SWZ
        float hnew = fast_tanh(v + zv);
        _Float16 h16v = (_Float16)hnew;
        ((_Float16*)hbuf[cur ^ 1])[hphys * 8 + (tid & 7)] = h16v;
        if (hs_out) hs_out[t * HDIM + tid] = h16v;
        if (hfin_out && t == nsteps - 1) hfin_out[tid] = h16v;
        __syncthreads();
        cur ^= 1;
    }
}

// ---------------------------------------------------------------------------
// Convert fc_w f32 -> f16 once
// ---------------------------------------------------------------------------
__global__ void __launch_bounds__(256) cvt_w16(const float* __restrict__ src,
                                               _Float16* __restrict__ dst, long n) {
    long i = ((long)blockIdx.x * 256 + threadIdx.x) * 8;
    if (i + 8 <= n) {
        const float4* s4 = (const float4*)(src + i);
        float4 a = s4[0], b = s4[1];
        half8_t o;
        o[0] = (_Float16)a.x; o[1] = (_Float16)a.y;
        o[2] = (_Float16)a.z; o[3] = (_Float16)a.w;
        o[4] = (_Float16)b.x; o[5] = (_Float16)b.y;
        o[6] = (_Float16)b.z; o[7] = (_Float16)b.w;
        *(half8_t*)(dst + i) = o;
    }
}

// ---------------------------------------------------------------------------
// FC: out[m][n] = sum_k A16[m][k] * B16[n][k] + fc_b[n]
// M=512, N=50257, K=512. f16 MFMA 16x16x32, direct global frags (B is f16).
// ---------------------------------------------------------------------------
__global__ void __launch_bounds__(256) fc_ker16(const _Float16* __restrict__ A,
                                                const _Float16* __restrict__ Bw,
                                                const float* __restrict__ bias,
                                                float* __restrict__ out) {
    int n0 = blockIdx.x * 128, m0 = blockIdx.y * 128;
    int w = threadIdx.x >> 6, l = threadIdx.x & 63;
    int wm = (w >> 1) * 64, wn = (w & 1) * 64;
    int lr = l & 15, lk = (l >> 4) * 8;

    float4_t acc[4][4];
#pragma unroll
    for (int fm = 0; fm < 4; ++fm)
#pragma unroll
        for (int fn = 0; fn < 4; ++fn) acc[fm][fn] = (float4_t){0.f, 0.f, 0.f, 0.f};

    for (int ks = 0; ks < 512; ks += 32) {
        half8_t a[4], b[4];
#pragma unroll
        for (int f = 0; f < 4; ++f) {
            int m = m0 + wm + f * 16 + lr;
            a[f] = *(const half8_t*)(A + (long)m * 512 + ks + lk);
            int n = n0 + wn + f * 16 + lr;
            if (n < CDIM) {
                b[f] = *(const half8_t*)(Bw + (long)n * 512 + ks + lk);
            } else {
#pragma unroll
                for (int e = 0; e < 8; ++e) b[f][e] = (_Float16)0.f;
            }
        }
#pragma unroll
        for (int fm = 0; fm < 4; ++fm)
#pragma unroll
            for (int fn = 0; fn < 4; ++fn)
                acc[fm][fn] = __builtin_amdgcn_mfma_f32_16x16x32_f16(
                    a[fm], b[fn], acc[fm][fn], 0, 0, 0);
    }
#pragma unroll
    for (int fn = 0; fn < 4; ++fn) {
        int n = n0 + wn + fn * 16 + lr;
        if (n >= CDIM) continue;
        float bv = bias[n];
#pragma unroll
        for (int fm = 0; fm < 4; ++fm) {
#pragma unroll
            for (int q = 0; q < 4; ++q) {
                int m = m0 + wm + fm * 16 + (l >> 4) * 4 + q;
                out[(long)m * CDIM + n] = acc[fm][fn][q] + bv;
            }
        }
    }
}

// Fallback FC reading f32 B with inline conversion (if ws too small for f16 B)
__global__ void __launch_bounds__(256) fc_ker(const _Float16* __restrict__ A,
                                              const float* __restrict__ Bw,
                                              const float* __restrict__ bias,
                                              float* __restrict__ out) {
    int n0 = blockIdx.x * 128, m0 = blockIdx.y * 128;
    int w = threadIdx.x >> 6, l = threadIdx.x & 63;
    int wm = (w >> 1) * 64, wn = (w & 1) * 64;
    int lr = l & 15, lk = (l >> 4) * 8;

    float4_t acc[4][4];
#pragma unroll
    for (int fm = 0; fm < 4; ++fm)
#pragma unroll
        for (int fn = 0; fn < 4; ++fn) acc[fm][fn] = (float4_t){0.f, 0.f, 0.f, 0.f};

    for (int ks = 0; ks < 512; ks += 32) {
        half8_t a[4], b[4];
#pragma unroll
        for (int f = 0; f < 4; ++f) {
            int m = m0 + wm + f * 16 + lr;
            a[f] = *(const half8_t*)(A + (long)m * 512 + ks + lk);
            int n = n0 + wn + f * 16 + lr;
            half8_t bb;
            if (n < CDIM) {
                const float4* bp4 = (const float4*)(Bw + (long)n * 512 + ks + lk);
                float4 x0 = bp4[0], x1 = bp4[1];
                bb[0] = (_Float16)x0.x; bb[1] = (_Float16)x0.y;
                bb[2] = (_Float16)x0.z; bb[3] = (_Float16)x0.w;
                bb[4] = (_Float16)x1.x; bb[5] = (_Float16)x1.y;
                bb[6] = (_Float16)x1.z; bb[7] = (_Float16)x1.w;
            } else {
#pragma unroll
                for (int e = 0; e < 8; ++e) bb[e] = (_Float16)0.f;
            }
            b[f] = bb;
        }
#pragma unroll
        for (int fm = 0; fm < 4; ++fm)
#pragma unroll
            for (int fn = 0; fn < 4; ++fn)
                acc[fm][fn] = __builtin_amdgcn_mfma_f32_16x16x32_f16(
                    a[fm], b[fn], acc[fm][fn], 0, 0, 0);
    }
#pragma unroll
    for (int fn = 0; fn < 4; ++fn) {
        int n = n0 + wn + fn * 16 + lr;
        if (n >= CDIM) continue;
        float bv = bias[n];
#pragma unroll
        for (int fm = 0; fm < 4; ++fm) {
#pragma unroll
            for (int q = 0; q < 4; ++q) {
                int m = m0 + wm + fm * 16 + (l >> 4) * 4 + q;
                out[(long)m * CDIM + n] = acc[fm][fn][q] + bv;
            }
        }
    }
}

// ---------------------------------------------------------------------------
// Workspace layout:
//   [0, 2MB)          z  f32 [1024][512]
//   [2MB, 2.5MB)      wpack_enc f16
//   [2.5MB, 3MB)      wpack_dec f16
//   [3MB, 3.5MB)      h16 f16 [512][512]  (decoder hidden states = FC A matrix)
//   [3.5MB, +1KB)     hn16 f16 [512]      (encoder final hidden)
//   [4MB, 4MB+51.5MB) fc_w16 (only if ws_size permits)
// ---------------------------------------------------------------------------
extern "C" void kernel_launch(void* const* d_in, const int* in_sizes, int n_in,
                              void* d_out, int out_size, void* d_ws, size_t ws_size,
                              hipStream_t stream) {
    const int* input_ids  = (const int*)d_in[1];
    const int* output_ids = (const int*)d_in[2];
    const float* emb      = (const float*)d_in[3];
    const float* enc_wih  = (const float*)d_in[4];
    const float* enc_whh  = (const float*)d_in[5];
    const float* enc_bih  = (const float*)d_in[6];
    const float* enc_bhh  = (const float*)d_in[7];
    const float* dec_wih  = (const float*)d_in[8];
    const float* dec_whh  = (const float*)d_in[9];
    const float* dec_bih  = (const float*)d_in[10];
    const float* dec_bhh  = (const float*)d_in[11];
    const float* fc_w     = (const float*)d_in[12];
    const float* fc_b     = (const float*)d_in[13];
    float* out = (float*)d_out;

    char* ws = (char*)d_ws;
    float* z        = (float*)ws;                                  // 2 MB
    _Float16* wpe   = (_Float16*)(ws + (2u << 20));                // 512 KB
    _Float16* wpd   = (_Float16*)(ws + (2u << 20) + (512u << 10)); // 512 KB
    _Float16* h16   = (_Float16*)(ws + (3u << 20));                // 512 KB
    _Float16* hn16  = (_Float16*)(ws + (3u << 20) + (512u << 10)); // 1 KB
    _Float16* fcw16 = (_Float16*)(ws + (4u << 20));                // 51.5 MB

    const long fcw_n = (long)CDIM * HDIM;
    bool use_f16_fc = ws_size >= (size_t)(4u << 20) + (size_t)fcw_n * 2;

    pack_whh<<<128, 256, 0, stream>>>(enc_whh, wpe);
    pack_whh<<<128, 256, 0, stream>>>(dec_whh, wpd);
    if (use_f16_fc) {
        int nb = (int)((fcw_n / 8 + 255) / 256);
        cvt_w16<<<nb, 256, 0, stream>>>(fc_w, fcw16, fcw_n);
    }
    zker<<<1024, 256, 0, stream>>>(input_ids, output_ids, emb,
                                   enc_wih, enc_bih, enc_bhh,
                                   dec_wih, dec_bih, dec_bhh, z);
    // encoder: h starts at 0, produce hn16
    scan_ker<<<1, 512, 0, stream>>>(wpe, z, nullptr, nullptr, hn16, 512);
    // decoder: h starts at hn16, produce all 512 hidden states
    scan_ker<<<1, 512, 0, stream>>>(wpd, z + 512 * HDIM, hn16, h16, nullptr, 512);
    if (use_f16_fc)
        fc_ker16<<<dim3((CDIM + 127) / 128, 4), 256, 0, stream>>>(h16, fcw16, fc_b, out);
    else
        fc_ker<<<dim3((CDIM + 127) / 128, 4), 256, 0, stream>>>(h16, fc_w, fc_b, out);
}

// Round 6
// 1626.182 us; speedup vs baseline: 1.9686x; 1.1069x over previous
//
#include <hip/hip_runtime.h>
#include <hip/hip_fp16.h>

#define EDIM 256
#define HDIM 512
#define CDIM 50257

using half2_t = __attribute__((ext_vector_type(2))) _Float16;
using half8_t = __attribute__((ext_vector_type(8))) _Float16;
using float4_t = __attribute__((ext_vector_type(4))) float;

__device__ __forceinline__ float dot2(uint32_t w, uint32_t h, float acc) {
    return __builtin_amdgcn_fdot2(__builtin_bit_cast(half2_t, w),
                                  __builtin_bit_cast(half2_t, h), acc, false);
}

// tanh(x) = 1 - 2/(exp2(2x*log2e)+1): ~5 VALU instrs vs ~30 for tanhf libcall
__device__ __forceinline__ float fast_tanh(float x) {
    float e = __builtin_amdgcn_exp2f(x * 2.8853900817779268f);
    return 1.f - 2.f * __builtin_amdgcn_rcpf(e + 1.f);
}

// ---------------------------------------------------------------------------
// Pack whh (f32 [512][512]) -> f16 granules [g=0..63][t=0..511][8 halves].
// Scan thread t: rg = t>>4 (row group of 16), c = t&15 (32-wide k chunk).
// g = jr*4 + i  (jr 0..15 row-within-group, i 0..3 granule-within-k-chunk):
//   granule holds whh[rg*16 + jr][c*32 + i*8 + e], e = 0..7.
// jr 0..11 -> register-resident in scan; jr 12..15 -> streamed from LDS.
// ---------------------------------------------------------------------------
__global__ void __launch_bounds__(256) pack_whh(const float* __restrict__ whh,
                                                _Float16* __restrict__ wpack) {
    int idx = blockIdx.x * blockDim.x + threadIdx.x;   // 0..32767
    int g = idx >> 9, t = idx & 511;
    int jr = g >> 2, i = g & 3;
    int row = ((t >> 4) << 4) + jr;
    int k0 = ((t & 15) << 5) + (i << 3);
    const float* src = whh + row * HDIM + k0;
    uint32_t d[4];
#pragma unroll
    for (int q = 0; q < 4; ++q) {
        half2_t p;
        p[0] = (_Float16)src[2 * q];
        p[1] = (_Float16)src[2 * q + 1];
        d[q] = __builtin_bit_cast(uint32_t, p);
    }
    ((uint4*)wpack)[g * 512 + t] = make_uint4(d[0], d[1], d[2], d[3]);
}

// ---------------------------------------------------------------------------
// z[t][r] = dot(wih[r,:], emb[id_t]) + bih[r] + bhh[r]   (fp32, parallel)
// ---------------------------------------------------------------------------
__global__ void __launch_bounds__(256) zker(const int* __restrict__ in_ids,
                                            const int* __restrict__ out_ids,
                                            const float* __restrict__ emb,
                                            const float* __restrict__ enc_wih,
                                            const float* __restrict__ enc_bih,
                                            const float* __restrict__ enc_bhh,
                                            const float* __restrict__ dec_wih,
                                            const float* __restrict__ dec_bih,
                                            const float* __restrict__ dec_bhh,
                                            float* __restrict__ z) {
    int t = blockIdx.x;
    const float *wih, *bih, *bhh;
    int id;
    if (t < 512) {
        wih = enc_wih; bih = enc_bih; bhh = enc_bhh; id = in_ids[t];
    } else {
        wih = dec_wih; bih = dec_bih; bhh = dec_bhh;
        id = (t == 512) ? 1 : out_ids[t - 513];
    }
    __shared__ float x[EDIM];
    x[threadIdx.x] = emb[(long)id * EDIM + threadIdx.x];
    __syncthreads();
#pragma unroll
    for (int rr = 0; rr < 2; ++rr) {
        int r = threadIdx.x + rr * 256;
        const float4* w4 = (const float4*)(wih + r * EDIM);
        float acc = 0.f;
#pragma unroll 8
        for (int k4 = 0; k4 < 64; ++k4) {
            float4 wv = w4[k4];
            acc += wv.x * x[k4 * 4 + 0] + wv.y * x[k4 * 4 + 1] +
                   wv.z * x[k4 * 4 + 2] + wv.w * x[k4 * 4 + 3];
        }
        z[t * HDIM + r] = acc + bih[r] + bhh[r];
    }
}

// ---------------------------------------------------------------------------
// Sequential RNN scan: 1 workgroup, 512 threads (8 waves, 2/SIMD).
// Thread t: rg = t>>4 owns rows [rg*16, rg*16+16), c = t&15 owns k-slice
// [c*32, c*32+32). 12/16 rows register-resident (192 words), 4/16 streamed
// from LDS (128 KB, same bytes as R1). h kept f16 in LDS, double-buffered,
// TRANSPOSED granule layout [i][c] so each wave hg-read touches 16 distinct
// granules spread over all 32 banks (2-way aliasing = free). h traffic is
// HALVED vs R1 (4 vs 8 ds_read_b128/thread/step). Fold 15 levels: xor1/xor2
// via DPP quad_perm, xor8 via DPP row_ror:8, only xor4 on DS (ds_swizzle).
// Fast inline tanh. One barrier per step.
// ---------------------------------------------------------------------------
__global__ void __launch_bounds__(512, 2) scan_ker(
    const _Float16* __restrict__ wpack,   // [64][512][8] f16, see pack_whh
    const float* __restrict__ z,          // [nsteps][512] f32
    const _Float16* __restrict__ h_init,  // null => zeros; else [512] plain
    _Float16* __restrict__ hs_out,        // null or [nsteps][512] plain
    _Float16* __restrict__ hfin_out,      // null or [512] plain
    int nsteps) {
    __shared__ uint4 wlds[16 * 512];   // 128 KB: streamed rows jr=12..15
    __shared__ uint4 hbuf4[2][64];     // 2 KB: h granules, layout [i][c]

    const int tid = threadIdx.x;
    const int c = tid & 15;
    // h element OWNED by this thread after the fold is h[tid].
    // Logical granule g_own = tid>>3 holds elems [8*g_own, 8*g_own+8).
    // Physical f16 index of granule g is 128*(g&3) + 8*(g>>2)  ([i][c] layout),
    // so element tid sits at:
    const int g_own = tid >> 3;
    const int hstore = 128 * (g_own & 3) + 8 * (g_own >> 2) + (tid & 7);

    const uint4* wp4 = (const uint4*)wpack;
    uint32_t wreg[192];                // rows jr=0..11 (4 granules each)
#pragma unroll
    for (int g = 0; g < 48; ++g) {
        uint4 v = wp4[g * 512 + tid];
        wreg[g * 4 + 0] = v.x; wreg[g * 4 + 1] = v.y;
        wreg[g * 4 + 2] = v.z; wreg[g * 4 + 3] = v.w;
    }
#pragma unroll
    for (int g = 48; g < 64; ++g) wlds[(g - 48) * 512 + tid] = wp4[g * 512 + tid];

    ((_Float16*)hbuf4[0])[hstore] = h_init ? h_init[tid] : (_Float16)0.f;
    __syncthreads();

    int cur = 0;
    for (int t = 0; t < nsteps; ++t) {
        float zv = z[t * HDIM + tid];          // independent: scheduled early
        const uint4* hb = hbuf4[cur];
        float acc[16];
#pragma unroll
        for (int r = 0; r < 16; ++r) acc[r] = 0.f;
#pragma unroll
        for (int i = 0; i < 4; ++i) {
            uint4 hg = hb[i * 16 + c];         // h[k = c*32+i*8 .. +8)
#pragma unroll
            for (int jr = 0; jr < 12; ++jr) {
                acc[jr] = dot2(wreg[(jr * 4 + i) * 4 + 0], hg.x, acc[jr]);
                acc[jr] = dot2(wreg[(jr * 4 + i) * 4 + 1], hg.y, acc[jr]);
                acc[jr] = dot2(wreg[(jr * 4 + i) * 4 + 2], hg.z, acc[jr]);
                acc[jr] = dot2(wreg[(jr * 4 + i) * 4 + 3], hg.w, acc[jr]);
            }
#pragma unroll
            for (int js = 0; js < 4; ++js) {
                uint4 w = wlds[(js * 4 + i) * 512 + tid];
                acc[12 + js] = dot2(w.x, hg.x, acc[12 + js]);
                acc[12 + js] = dot2(w.y, hg.y, acc[12 + js]);
                acc[12 + js] = dot2(w.z, hg.z, acc[12 + js]);
                acc[12 + js] = dot2(w.w, hg.w, acc[12 + js]);
            }
        }
        // Fold 16 accs over the 4 bits of c; lane c ends with row rg*16+c.
        // Level pairing chosen so the only non-DPP exchange (xor4) is last.
        float s, keep;
#define FOLD_DPP(aL, aH, bit, ctrl, dst)                                      \
        s = (c & bit) ? (aL) : (aH);                                          \
        s = __builtin_bit_cast(float, __builtin_amdgcn_mov_dpp(               \
                __builtin_bit_cast(int, s), ctrl, 0xF, 0xF, true));           \
        keep = (c & bit) ? (aH) : (aL);                                       \
        dst = keep + s;
#define FOLD_SWZ(aL, aH, bit, pat, dst)                                       \
        s = (c & bit) ? (aL) : (aH);                                          \
        s = __builtin_bit_cast(float, __builtin_amdgcn_ds_swizzle(            \
                __builtin_bit_cast(int, s), pat));                            \
        keep = (c & bit) ? (aH) : (aL);                                       \
        dst = keep + s;
        float b0, b1, b2, b3, b4, b5, b6, b7, d0, d1, d2, d3, e0, e1, v;
        // L1: row bit0 <- c bit0 (xor1, quad_perm 1,0,3,2)
        FOLD_DPP(acc[0],  acc[1],  1, 0xB1, b0)
        FOLD_DPP(acc[2],  acc[3],  1, 0xB1, b1)
        FOLD_DPP(acc[4],  acc[5],  1, 0xB1, b2)
        FOLD_DPP(acc[6],  acc[7],  1, 0xB1, b3)
        FOLD_DPP(acc[8],  acc[9],  1, 0xB1, b4)
        FOLD_DPP(acc[10], acc[11], 1, 0xB1, b5)
        FOLD_DPP(acc[12], acc[13], 1, 0xB1, b6)
        FOLD_DPP(acc[14], acc[15], 1, 0xB1, b7)
        // L2: row bit1 <- c bit1 (xor2, quad_perm 2,3,0,1)
        FOLD_DPP(b0, b1, 2, 0x4E, d0)   // d0: bits(3,2)=(0,0)
        FOLD_DPP(b2, b3, 2, 0x4E, d1)   // d1: (0,1)
        FOLD_DPP(b4, b5, 2, 0x4E, d2)   // d2: (1,0)
        FOLD_DPP(b6, b7, 2, 0x4E, d3)   // d3: (1,1)
        // L3: row bit3 <- c bit3 (xor8 == row_ror:8 within 16-lane row)
        FOLD_DPP(d0, d2, 8, 0x128, e0)  // e0: bit2=0
        FOLD_DPP(d1, d3, 8, 0x128, e1)  // e1: bit2=1
        // L4: row bit2 <- c bit2 (xor4 via ds_swizzle)
        FOLD_SWZ(e0, e1, 4, 0x101F, v)
#undef FOLD_DPP
#undef FOLD_SWZ
        float hnew = fast_tanh(v + zv);
        _Float16 h16v = (_Float16)hnew;
        ((_Float16*)hbuf4[cur ^ 1])[hstore] = h16v;
        if (hs_out) hs_out[t * HDIM + tid] = h16v;
        if (hfin_out && t == nsteps - 1) hfin_out[tid] = h16v;
        __syncthreads();
        cur ^= 1;
    }
}

// ---------------------------------------------------------------------------
// Convert fc_w f32 -> f16 once
// ---------------------------------------------------------------------------
__global__ void __launch_bounds__(256) cvt_w16(const float* __restrict__ src,
                                               _Float16* __restrict__ dst, long n) {
    long i = ((long)blockIdx.x * 256 + threadIdx.x) * 8;
    if (i + 8 <= n) {
        const float4* s4 = (const float4*)(src + i);
        float4 a = s4[0], b = s4[1];
        half8_t o;
        o[0] = (_Float16)a.x; o[1] = (_Float16)a.y;
        o[2] = (_Float16)a.z; o[3] = (_Float16)a.w;
        o[4] = (_Float16)b.x; o[5] = (_Float16)b.y;
        o[6] = (_Float16)b.z; o[7] = (_Float16)b.w;
        *(half8_t*)(dst + i) = o;
    }
}

// ---------------------------------------------------------------------------
// FC: out[m][n] = sum_k A16[m][k] * B16[n][k] + fc_b[n]
// M=512, N=50257, K=512. f16 MFMA 16x16x32, direct global frags (B is f16).
// ---------------------------------------------------------------------------
__global__ void __launch_bounds__(256) fc_ker16(const _Float16* __restrict__ A,
                                                const _Float16* __restrict__ Bw,
                                                const float* __restrict__ bias,
                                                float* __restrict__ out) {
    int n0 = blockIdx.x * 128, m0 = blockIdx.y * 128;
    int w = threadIdx.x >> 6, l = threadIdx.x & 63;
    int wm = (w >> 1) * 64, wn = (w & 1) * 64;
    int lr = l & 15, lk = (l >> 4) * 8;

    float4_t acc[4][4];
#pragma unroll
    for (int fm = 0; fm < 4; ++fm)
#pragma unroll
        for (int fn = 0; fn < 4; ++fn) acc[fm][fn] = (float4_t){0.f, 0.f, 0.f, 0.f};

    for (int ks = 0; ks < 512; ks += 32) {
        half8_t a[4], b[4];
#pragma unroll
        for (int f = 0; f < 4; ++f) {
            int m = m0 + wm + f * 16 + lr;
            a[f] = *(const half8_t*)(A + (long)m * 512 + ks + lk);
            int n = n0 + wn + f * 16 + lr;
            if (n < CDIM) {
                b[f] = *(const half8_t*)(Bw + (long)n * 512 + ks + lk);
            } else {
#pragma unroll
                for (int e = 0; e < 8; ++e) b[f][e] = (_Float16)0.f;
            }
        }
#pragma unroll
        for (int fm = 0; fm < 4; ++fm)
#pragma unroll
            for (int fn = 0; fn < 4; ++fn)
                acc[fm][fn] = __builtin_amdgcn_mfma_f32_16x16x32_f16(
                    a[fm], b[fn], acc[fm][fn], 0, 0, 0);
    }
#pragma unroll
    for (int fn = 0; fn < 4; ++fn) {
        int n = n0 + wn + fn * 16 + lr;
        if (n >= CDIM) continue;
        float bv = bias[n];
#pragma unroll
        for (int fm = 0; fm < 4; ++fm) {
#pragma unroll
            for (int q = 0; q < 4; ++q) {
                int m = m0 + wm + fm * 16 + (l >> 4) * 4 + q;
                out[(long)m * CDIM + n] = acc[fm][fn][q] + bv;
            }
        }
    }
}

// Fallback FC reading f32 B with inline conversion (if ws too small for f16 B)
__global__ void __launch_bounds__(256) fc_ker(const _Float16* __restrict__ A,
                                              const float* __restrict__ Bw,
                                              const float* __restrict__ bias,
                                              float* __restrict__ out) {
    int n0 = blockIdx.x * 128, m0 = blockIdx.y * 128;
    int w = threadIdx.x >> 6, l = threadIdx.x & 63;
    int wm = (w >> 1) * 64, wn = (w & 1) * 64;
    int lr = l & 15, lk = (l >> 4) * 8;

    float4_t acc[4][4];
#pragma unroll
    for (int fm = 0; fm < 4; ++fm)
#pragma unroll
        for (int fn = 0; fn < 4; ++fn) acc[fm][fn] = (float4_t){0.f, 0.f, 0.f, 0.f};

    for (int ks = 0; ks < 512; ks += 32) {
        half8_t a[4], b[4];
#pragma unroll
        for (int f = 0; f < 4; ++f) {
            int m = m0 + wm + f * 16 + lr;
            a[f] = *(const half8_t*)(A + (long)m * 512 + ks + lk);
            int n = n0 + wn + f * 16 + lr;
            half8_t bb;
            if (n < CDIM) {
                const float4* bp4 = (const float4*)(Bw + (long)n * 512 + ks + lk);
                float4 x0 = bp4[0], x1 = bp4[1];
                bb[0] = (_Float16)x0.x; bb[1] = (_Float16)x0.y;
                bb[2] = (_Float16)x0.z; bb[3] = (_Float16)x0.w;
                bb[4] = (_Float16)x1.x; bb[5] = (_Float16)x1.y;
                bb[6] = (_Float16)x1.z; bb[7] = (_Float16)x1.w;
            } else {
#pragma unroll
                for (int e = 0; e < 8; ++e) bb[e] = (_Float16)0.f;
            }
            b[f] = bb;
        }
#pragma unroll
        for (int fm = 0; fm < 4; ++fm)
#pragma unroll
            for (int fn = 0; fn < 4; ++fn)
                acc[fm][fn] = __builtin_amdgcn_mfma_f32_16x16x32_f16(
                    a[fm], b[fn], acc[fm][fn], 0, 0, 0);
    }
#pragma unroll
    for (int fn = 0; fn < 4; ++fn) {
        int n = n0 + wn + fn * 16 + lr;
        if (n >= CDIM) continue;
        float bv = bias[n];
#pragma unroll
        for (int fm = 0; fm < 4; ++fm) {
#pragma unroll
            for (int q = 0; q < 4; ++q) {
                int m = m0 + wm + fm * 16 + (l >> 4) * 4 + q;
                out[(long)m * CDIM + n] = acc[fm][fn][q] + bv;
            }
        }
    }
}

// ---------------------------------------------------------------------------
// Workspace layout:
//   [0, 2MB)          z  f32 [1024][512]
//   [2MB, 2.5MB)      wpack_enc f16
//   [2.5MB, 3MB)      wpack_dec f16
//   [3MB, 3.5MB)      h16 f16 [512][512]  (decoder hidden states = FC A matrix)
//   [3.5MB, +1KB)     hn16 f16 [512]      (encoder final hidden)
//   [4MB, 4MB+51.5MB) fc_w16 (only if ws_size permits)
// ---------------------------------------------------------------------------
extern "C" void kernel_launch(void* const* d_in, const int* in_sizes, int n_in,
                              void* d_out, int out_size, void* d_ws, size_t ws_size,
                              hipStream_t stream) {
    const int* input_ids  = (const int*)d_in[1];
    const int* output_ids = (const int*)d_in[2];
    const float* emb      = (const float*)d_in[3];
    const float* enc_wih  = (const float*)d_in[4];
    const float* enc_whh  = (const float*)d_in[5];
    const float* enc_bih  = (const float*)d_in[6];
    const float* enc_bhh  = (const float*)d_in[7];
    const float* dec_wih  = (const float*)d_in[8];
    const float* dec_whh  = (const float*)d_in[9];
    const float* dec_bih  = (const float*)d_in[10];
    const float* dec_bhh  = (const float*)d_in[11];
    const float* fc_w     = (const float*)d_in[12];
    const float* fc_b     = (const float*)d_in[13];
    float* out = (float*)d_out;

    char* ws = (char*)d_ws;
    float* z        = (float*)ws;                                  // 2 MB
    _Float16* wpe   = (_Float16*)(ws + (2u << 20));                // 512 KB
    _Float16* wpd   = (_Float16*)(ws + (2u << 20) + (512u << 10)); // 512 KB
    _Float16* h16   = (_Float16*)(ws + (3u << 20));                // 512 KB
    _Float16* hn16  = (_Float16*)(ws + (3u << 20) + (512u << 10)); // 1 KB
    _Float16* fcw16 = (_Float16*)(ws + (4u << 20));                // 51.5 MB

    const long fcw_n = (long)CDIM * HDIM;
    bool use_f16_fc = ws_size >= (size_t)(4u << 20) + (size_t)fcw_n * 2;

    pack_whh<<<128, 256, 0, stream>>>(enc_whh, wpe);
    pack_whh<<<128, 256, 0, stream>>>(dec_whh, wpd);
    if (use_f16_fc) {
        int nb = (int)((fcw_n / 8 + 255) / 256);
        cvt_w16<<<nb, 256, 0, stream>>>(fc_w, fcw16, fcw_n);
    }
    zker<<<1024, 256, 0, stream>>>(input_ids, output_ids, emb,
                                   enc_wih, enc_bih, enc_bhh,
                                   dec_wih, dec_bih, dec_bhh, z);
    // encoder: h starts at 0, produce hn16
    scan_ker<<<1, 512, 0, stream>>>(wpe, z, nullptr, nullptr, hn16, 512);
    // decoder: h starts at hn16, produce all 512 hidden states
    scan_ker<<<1, 512, 0, stream>>>(wpd, z + 512 * HDIM, hn16, h16, nullptr, 512);
    if (use_f16_fc)
        fc_ker16<<<dim3((CDIM + 127) / 128, 4), 256, 0, stream>>>(h16, fcw16, fc_b, out);
    else
        fc_ker<<<dim3((CDIM + 127) / 128, 4), 256, 0, stream>>>(h16, fc_w, fc_b, out);
}